// Round 1
// 443.172 us; speedup vs baseline: 1.0338x; 1.0338x over previous
//
#include <hip/hip_runtime.h>

#define N_NODES 100000
#define N_EDGES 1000000
#define D_FEAT  6
#define HIDDEN  300
#define HID_P   320          // padded hidden (multiple of 32)
#define MSG     100
#define OUTC    200          // 2*MSG
#define OUTC_P  208
#define MT      64           // edges per block
#define NT_H    (HID_P/16)   // 20 feature tiles for hidden layers
#define NT_M    (OUTC_P/16)  // 13 feature tiles for messages
#define KS_H    (HID_P/32)   // 10 k-steps of 32

typedef __bf16 bf16_t;
typedef __bf16 bf16x8 __attribute__((ext_vector_type(8)));
typedef __bf16 bf16x4 __attribute__((ext_vector_type(4)));
typedef __bf16 bf16x2 __attribute__((ext_vector_type(2)));
typedef float  floatx4 __attribute__((ext_vector_type(4)));

// ---------------- prep (weight pack) + base MAE loss, merged --------------------
// B-frag order pack (doubles as A-frag order under operand swap — same index map):
// chunk of 512 el = one (ft,ks) fragment: el = ((ft*KS+ks)*64+lane)*8+j,
// element = W[k][n], n = ft*16+(lane&15), k = ks*32+(lane>>4)*8+j, zero-padded.
#define PREP_BLOCKS 700
#define LOSS_BLOCKS 200
__global__ void prep_kernel(const float* __restrict__ W1, const float* __restrict__ W2,
                            const float* __restrict__ W3, bf16_t* __restrict__ W1P,
                            bf16_t* __restrict__ W2P, bf16_t* __restrict__ W3P,
                            const float* __restrict__ y, const float* __restrict__ t,
                            float* __restrict__ out) {
    if (blockIdx.x >= PREP_BLOCKS) {
        float s = 0.f;
        for (int i = (blockIdx.x - PREP_BLOCKS) * blockDim.x + threadIdx.x;
             i < N_NODES * 2; i += LOSS_BLOCKS * blockDim.x)
            s += fabsf(y[i] - t[i]);
        #pragma unroll
        for (int off = 32; off; off >>= 1) s += __shfl_down(s, off);
        __shared__ float red[4];
        if ((threadIdx.x & 63) == 0) red[threadIdx.x >> 6] = s;
        __syncthreads();
        if (threadIdx.x == 0)
            atomicAdd(out, (red[0] + red[1] + red[2] + red[3]) * (1.0f / N_NODES));
        return;
    }
    const int n1 = NT_H * 512;
    const int n2 = NT_H * KS_H * 512;
    const int n3 = NT_M * KS_H * 512;
    const int total = n1 + n2 + n3;
    for (int id = blockIdx.x * blockDim.x + threadIdx.x; id < total;
         id += PREP_BLOCKS * blockDim.x) {
        if (id < n1) {
            int nt = id >> 9, rem = id & 511, lane = rem >> 3, j = rem & 7;
            int n = nt * 16 + (lane & 15), k = (lane >> 4) * 8 + j;
            float v = (n < HIDDEN && k < 2 * D_FEAT) ? W1[k * HIDDEN + n] : 0.f;
            W1P[id] = (bf16_t)v;
        } else if (id < n1 + n2) {
            int r = id - n1;
            int chunk = r >> 9, rem = r & 511, lane = rem >> 3, j = rem & 7;
            int ks = chunk % KS_H, nt = chunk / KS_H;
            int n = nt * 16 + (lane & 15), k = ks * 32 + (lane >> 4) * 8 + j;
            float v = (n < HIDDEN && k < HIDDEN) ? W2[k * HIDDEN + n] : 0.f;
            W2P[r] = (bf16_t)v;
        } else {
            int r = id - n1 - n2;
            int chunk = r >> 9, rem = r & 511, lane = rem >> 3, j = rem & 7;
            int ks = chunk % KS_H, nt = chunk / KS_H;
            int n = nt * 16 + (lane & 15), k = ks * 32 + (lane >> 4) * 8 + j;
            float v = (n < OUTC && k < HIDDEN) ? W3[k * OUTC + n] : 0.f;
            W3P[r] = (bf16_t)v;
        }
    }
}

static __device__ __forceinline__ floatx4 mfma16(bf16x8 a, bf16x8 b, floatx4 c) {
    return __builtin_amdgcn_mfma_f32_16x16x32_bf16(a, b, c, 0, 0, 0);
}

// Balanced GEMM phase: 80 jobs = 20 nt x 4 e-tiles, exactly 10 per wave as
// 2 full nts (4 e) + 1 half nt (2 e). PE0 (compile-time, 0 or 2) = e-base of the
// half tile, so every register index is compile-time (rule #20). Each h-fragment
// is consumed immediately by its 2-3 MFMAs -> at most 1 h + 3 w frags live.
template<int PE0, int KSN, int SE>
__device__ __forceinline__ void gemm_phase(
    const bf16_t* __restrict__ Wp, const bf16_t* __restrict__ Hsrc, int lane,
    int ntA, int ntB, int ntP,
    floatx4 (&aA)[4], floatx4 (&aB)[4], floatx4 (&aP)[2]) {
    #pragma unroll
    for (int e = 0; e < 4; e++) {
        aA[e] = (floatx4){0.f, 0.f, 0.f, 0.f};
        aB[e] = (floatx4){0.f, 0.f, 0.f, 0.f};
    }
    aP[0] = (floatx4){0.f, 0.f, 0.f, 0.f};
    aP[1] = (floatx4){0.f, 0.f, 0.f, 0.f};
    #pragma unroll 2
    for (int ks = 0; ks < KSN; ks++) {
        const bf16_t* wb = Wp + ks * 512 + lane * 8;
        bf16x8 wfA = *(const bf16x8*)(wb + ntA * (KSN * 512));
        bf16x8 wfB = *(const bf16x8*)(wb + ntB * (KSN * 512));
        bf16x8 wfP = *(const bf16x8*)(wb + ntP * (KSN * 512));
        const bf16_t* hb = Hsrc + ks * 512 + lane * 8;
        bf16x8 h0 = *(const bf16x8*)(hb + 0 * SE);
        aA[0] = mfma16(wfA, h0, aA[0]);
        aB[0] = mfma16(wfB, h0, aB[0]);
        if (PE0 == 0) aP[0] = mfma16(wfP, h0, aP[0]);
        bf16x8 h1 = *(const bf16x8*)(hb + 1 * SE);
        aA[1] = mfma16(wfA, h1, aA[1]);
        aB[1] = mfma16(wfB, h1, aB[1]);
        if (PE0 == 0) aP[1] = mfma16(wfP, h1, aP[1]);
        bf16x8 h2 = *(const bf16x8*)(hb + 2 * SE);
        aA[2] = mfma16(wfA, h2, aA[2]);
        aB[2] = mfma16(wfB, h2, aB[2]);
        if (PE0 == 2) aP[0] = mfma16(wfP, h2, aP[0]);
        bf16x8 h3 = *(const bf16x8*)(hb + 3 * SE);
        aA[3] = mfma16(wfA, h3, aA[3]);
        aB[3] = mfma16(wfB, h3, aB[3]);
        if (PE0 == 2) aP[1] = mfma16(wfP, h3, aP[1]);
    }
}

// Epilogue for one job set: bias + relu + pack to bf16, write in B-frag order.
// C/D layout: n(edge)=lane&15, m(feat)=(lane>>4)*4+reg  (verified, absmax 0).
template<int NE>
__device__ __forceinline__ void epi_job(
    bf16_t* __restrict__ Hf, const float* __restrict__ bias,
    int nt, int q, int l16, int e0, const floatx4 (&acc)[NE]) {
    int n0 = nt * 16 + 4 * q;
    floatx4 bv = (n0 < HIDDEN) ? *(const floatx4*)&bias[n0]
                               : (floatx4){0.f, 0.f, 0.f, 0.f};
    int ks = n0 >> 5, lp = l16 + 16 * ((n0 >> 3) & 3), j0 = n0 & 7;
    #pragma unroll
    for (int p = 0; p < NE; p++) {
        bf16x4 pk;
        #pragma unroll
        for (int r = 0; r < 4; r++)
            pk[r] = (bf16_t)fmaxf(acc[p][r] + bv[r], 0.f);
        *(bf16x4*)&Hf[(((e0 + p) * KS_H + ks) * 64 + lp) * 8 + j0] = pk;
    }
}

template<int PE0>
__device__ __forceinline__ void epi_h(
    bf16_t* __restrict__ Hf, const float* __restrict__ bias, int q, int l16,
    int ntA, int ntB, int ntP,
    const floatx4 (&aA)[4], const floatx4 (&aB)[4], const floatx4 (&aP)[2]) {
    epi_job<4>(Hf, bias, ntA, q, l16, 0, aA);
    epi_job<4>(Hf, bias, ntB, q, l16, 0, aB);
    epi_job<2>(Hf, bias, ntP, q, l16, PE0, aP);
}

// ---------------- fused edge MLP + KL ------------------------------------------
// OPERAND SWAP: D = mfma(A=W_frag, B=H_frag) -> D rows = features, cols = edges.
// H lives in LDS in exact B-fragment order Hf[e][ks][lane][8] -> every read is a
// wave-contiguous 1KB ds_read_b128, every epilogue write is one ds_write_b64.
// Job balance: 20nt x 4e = 80 jobs = exactly 10/wave (2 full nts + 1 half nt,
// half's e-pair = (w&1)? {2,3} : {0,1}) -> max wave = avg wave at every barrier.
__global__ __launch_bounds__(512, 6) void mlp_kernel(
    const float* __restrict__ x, const int* __restrict__ ei,
    const bf16_t* __restrict__ W1P, const bf16_t* __restrict__ W2P,
    const bf16_t* __restrict__ W3P,
    const float* __restrict__ b1, const float* __restrict__ b2,
    const float* __restrict__ b3, float* __restrict__ out) {
    __shared__ __align__(16) bf16_t A1f[4 * 64 * 8];          // 4 KB, frag order
    __shared__ __align__(16) bf16_t Hf[4 * KS_H * 64 * 8];    // 40 KB, frag order
    __shared__ float red[8];

    const int tid  = threadIdx.x;
    const int w    = tid >> 6, lane = tid & 63;
    const int q    = lane >> 4, l16 = lane & 15;
    const long e0 = (long)blockIdx.x * MT;

    // balanced job params (wave-uniform scalars)
    const int base = (10 * w) >> 2;
    const int ntA = (w & 1) ? base + 1 : base;
    const int ntB = (w & 1) ? base + 2 : base + 1;
    const int ntP = (w & 1) ? base     : base + 2;

    // zero A1f (k >= 12 must be 0 for GEMM1's padded K=32)
    *(ulong*)&A1f[tid * 4] = 0ul;
    __syncthreads();
    // gather: edge features -> A1f fragment order: elem(lane',j) =
    // feat k of edge (et*16 + (lane'&15)), k = (lane'>>4)*8 + j
    if (tid < 2 * MT) {
        int m = tid >> 1, side = tid & 1;
        int node = ei[(long)side * N_EDGES + e0 + m];
        const float2* xr = (const float2*)(x + (long)node * D_FEAT);
        float2 v0 = xr[0], v1 = xr[1], v2 = xr[2];
        int et = m >> 4, ml = m & 15;
        bf16_t* Ab = &A1f[(et * 64 + ml) * 8];
        if (side == 0) {                       // k = 0..5 -> row ml, j 0..5
            bf16x4 lo = {(bf16_t)v0.x, (bf16_t)v0.y, (bf16_t)v1.x, (bf16_t)v1.y};
            *(bf16x4*)&Ab[0] = lo;
            bf16x2 mid = {(bf16_t)v2.x, (bf16_t)v2.y};
            *(bf16x2*)&Ab[4] = mid;
        } else {                               // k = 6,7 -> row ml; k = 8..11 -> row ml+16
            bf16x2 hi2 = {(bf16_t)v0.x, (bf16_t)v0.y};
            *(bf16x2*)&Ab[6] = hi2;
            bf16x4 top = {(bf16_t)v1.x, (bf16_t)v1.y, (bf16_t)v2.x, (bf16_t)v2.y};
            *(bf16x4*)&A1f[(et * 64 + ml + 16) * 8] = top;
        }
    }
    __syncthreads();

    floatx4 aA[4], aB[4], aP[2];

    // ---- GEMM1: h1 = relu(e @ W1 + b1), K=32 (one step) ----
    if (w & 1) {
        gemm_phase<2, 1, 512>(W1P, A1f, lane, ntA, ntB, ntP, aA, aB, aP);
        epi_h<2>(Hf, b1, q, l16, ntA, ntB, ntP, aA, aB, aP);
    } else {
        gemm_phase<0, 1, 512>(W1P, A1f, lane, ntA, ntB, ntP, aA, aB, aP);
        epi_h<0>(Hf, b1, q, l16, ntA, ntB, ntP, aA, aB, aP);
    }
    __syncthreads();

    // ---- GEMM2: h2 = relu(h1 @ W2 + b2), K=320 ----
    if (w & 1)
        gemm_phase<2, KS_H, KS_H * 512>(W2P, Hf, lane, ntA, ntB, ntP, aA, aB, aP);
    else
        gemm_phase<0, KS_H, KS_H * 512>(W2P, Hf, lane, ntA, ntB, ntP, aA, aB, aP);
    __syncthreads();   // all Hf(h1) reads done before overwrite
    if (w & 1)
        epi_h<2>(Hf, b2, q, l16, ntA, ntB, ntP, aA, aB, aP);
    else
        epi_h<0>(Hf, b2, q, l16, ntA, ntB, ntP, aA, aB, aP);
    __syncthreads();

    // ---- GEMM3: messages = h2 @ W3 + b3, KL in-register ----
    // 13 nt tiles: w<3 -> 1 tile (w), w>=3 -> 2 tiles (w, w+5)
    const int cnt_m = (w >= 3) ? 2 : 1;
    floatx4 acc3[2][4];
    #pragma unroll
    for (int t = 0; t < 2; t++)
        #pragma unroll
        for (int e = 0; e < 4; e++) acc3[t][e] = (floatx4){0.f, 0.f, 0.f, 0.f};
    #pragma unroll 2
    for (int ks = 0; ks < KS_H; ks++) {
        bf16x8 hb[4];
        #pragma unroll
        for (int e = 0; e < 4; e++)
            hb[e] = *(const bf16x8*)&Hf[((e * KS_H + ks) * 64 + lane) * 8];
        #pragma unroll
        for (int t = 0; t < 2; t++) {
            if (t < cnt_m) {
                bf16x8 wf = *(const bf16x8*)&W3P[(((w + 5 * t) * KS_H + ks) * 64 + lane) * 8];
                #pragma unroll
                for (int e = 0; e < 4; e++)
                    acc3[t][e] = mfma16(wf, hb[e], acc3[t][e]);
            }
        }
    }
    float s = 0.f;
    #pragma unroll
    for (int t = 0; t < 2; t++) {
        if (t < cnt_m) {
            int n0 = (w + 5 * t) * 16 + 4 * q;           // 4 consecutive features
            if (n0 < OUTC) {                              // runs never straddle 100/200
                floatx4 bv = *(const floatx4*)&b3[n0];
                bool is_mu = (n0 < MSG);
                #pragma unroll
                for (int e = 0; e < 4; e++)
                    #pragma unroll
                    for (int r = 0; r < 4; r++) {
                        float v = acc3[t][e][r] + bv[r];
                        if (is_mu) s += 0.5f * v * v;
                        else       s += 0.5f * (__expf(v) - v - 1.f);
                    }
            }
        }
    }
    #pragma unroll
    for (int off = 32; off; off >>= 1) s += __shfl_down(s, off);
    if (lane == 0) red[w] = s;
    __syncthreads();
    if (tid == 0) {
        float t2 = 0.f;
        #pragma unroll
        for (int i = 0; i < 8; i++) t2 += red[i];
        atomicAdd(out, t2 * (1.0f / N_EDGES));
    }
}

extern "C" void kernel_launch(void* const* d_in, const int* in_sizes, int n_in,
                              void* d_out, int out_size, void* d_ws, size_t ws_size,
                              hipStream_t stream) {
    const float* x      = (const float*)d_in[0];
    const int*   ei     = (const int*)d_in[1];
    const float* y      = (const float*)d_in[2];
    const float* target = (const float*)d_in[3];
    const float* W1     = (const float*)d_in[4];
    const float* b1     = (const float*)d_in[5];
    const float* W2     = (const float*)d_in[6];
    const float* b2     = (const float*)d_in[7];
    const float* W3     = (const float*)d_in[8];
    const float* b3     = (const float*)d_in[9];
    float* out = (float*)d_out;

    bf16_t* W1P = (bf16_t*)d_ws;
    bf16_t* W2P = W1P + NT_H * 512;
    bf16_t* W3P = W2P + NT_H * KS_H * 512;

    hipMemsetAsync(d_out, 0, sizeof(float), stream);
    prep_kernel<<<PREP_BLOCKS + LOSS_BLOCKS, 256, 0, stream>>>(
        W1, W2, W3, W1P, W2P, W3P, y, target, out);
    mlp_kernel<<<N_EDGES / MT, 512, 0, stream>>>(x, ei, W1P, W2P, W3P, b1, b2, b3, out);
}

// Round 2
// 411.034 us; speedup vs baseline: 1.1146x; 1.0782x over previous
//
#include <hip/hip_runtime.h>

#define N_NODES 100000
#define N_EDGES 1000000
#define D_FEAT  6
#define HIDDEN  300
#define HID_P   320          // padded hidden (multiple of 32)
#define MSG     100
#define OUTC    200          // 2*MSG
#define OUTC_P  208
#define MT      64           // edges per block
#define NT_H    (HID_P/16)   // 20 feature tiles for hidden layers
#define NT_M    13           // 13 feature tiles for messages (tile 12 partial)
#define KS_H    (HID_P/32)   // 10 k-steps of 32

typedef __bf16 bf16_t;
typedef __bf16 bf16x8 __attribute__((ext_vector_type(8)));
typedef __bf16 bf16x4 __attribute__((ext_vector_type(4)));
typedef __bf16 bf16x2 __attribute__((ext_vector_type(2)));
typedef float  floatx4 __attribute__((ext_vector_type(4)));

// ---------------- prep (weight pack) + base MAE loss, merged --------------------
// B-frag order pack (doubles as A-frag order under operand swap — same index map):
// chunk of 512 el = one (ft,ks) fragment: el = ((ft*KS+ks)*64+lane)*8+j,
// element = W[k][n], n = ft*16+(lane&15), k = ks*32+(lane>>4)*8+j, zero-padded.
#define PREP_BLOCKS 700
#define LOSS_BLOCKS 200
__global__ void prep_kernel(const float* __restrict__ W1, const float* __restrict__ W2,
                            const float* __restrict__ W3, bf16_t* __restrict__ W1P,
                            bf16_t* __restrict__ W2P, bf16_t* __restrict__ W3P,
                            const float* __restrict__ y, const float* __restrict__ t,
                            float* __restrict__ out) {
    if (blockIdx.x >= PREP_BLOCKS) {
        float s = 0.f;
        for (int i = (blockIdx.x - PREP_BLOCKS) * blockDim.x + threadIdx.x;
             i < N_NODES * 2; i += LOSS_BLOCKS * blockDim.x)
            s += fabsf(y[i] - t[i]);
        #pragma unroll
        for (int off = 32; off; off >>= 1) s += __shfl_down(s, off);
        __shared__ float red[4];
        if ((threadIdx.x & 63) == 0) red[threadIdx.x >> 6] = s;
        __syncthreads();
        if (threadIdx.x == 0)
            atomicAdd(out, (red[0] + red[1] + red[2] + red[3]) * (1.0f / N_NODES));
        return;
    }
    const int n1 = NT_H * 512;
    const int n2 = NT_H * KS_H * 512;
    const int n3 = NT_M * KS_H * 512;
    const int total = n1 + n2 + n3;
    for (int id = blockIdx.x * blockDim.x + threadIdx.x; id < total;
         id += PREP_BLOCKS * blockDim.x) {
        if (id < n1) {
            int nt = id >> 9, rem = id & 511, lane = rem >> 3, j = rem & 7;
            int n = nt * 16 + (lane & 15), k = (lane >> 4) * 8 + j;
            float v = (n < HIDDEN && k < 2 * D_FEAT) ? W1[k * HIDDEN + n] : 0.f;
            W1P[id] = (bf16_t)v;
        } else if (id < n1 + n2) {
            int r = id - n1;
            int chunk = r >> 9, rem = r & 511, lane = rem >> 3, j = rem & 7;
            int ks = chunk % KS_H, nt = chunk / KS_H;
            int n = nt * 16 + (lane & 15), k = ks * 32 + (lane >> 4) * 8 + j;
            float v = (n < HIDDEN && k < HIDDEN) ? W2[k * HIDDEN + n] : 0.f;
            W2P[r] = (bf16_t)v;
        } else {
            int r = id - n1 - n2;
            int chunk = r >> 9, rem = r & 511, lane = rem >> 3, j = rem & 7;
            int ks = chunk % KS_H, nt = chunk / KS_H;
            int n = nt * 16 + (lane & 15), k = ks * 32 + (lane >> 4) * 8 + j;
            float v = (n < OUTC && k < HIDDEN) ? W3[k * OUTC + n] : 0.f;
            W3P[r] = (bf16_t)v;
        }
    }
}

static __device__ __forceinline__ floatx4 mfma16(bf16x8 a, bf16x8 b, floatx4 c) {
    return __builtin_amdgcn_mfma_f32_16x16x32_bf16(a, b, c, 0, 0, 0);
}

// GEMM phase, 4-wave decomposition: wave w owns nts {5w..5w+4} x all 4 edge
// tiles = 20 jobs/wave, exactly balanced (80 jobs / 4 waves). Block-wide LDS
// h-reads per k-step = 4 waves x 4 = 16 (vs 32 with the 8-wave layout); each
// weight fragment still loaded exactly once per block.
template<int KSN, int SE>
__device__ __forceinline__ void gemm5x4(
    const bf16_t* __restrict__ Wbase0,     // W pack + (5w)*KSN*512
    const bf16_t* __restrict__ Hsrc, int lane, floatx4 (&acc)[5][4]) {
    #pragma unroll
    for (int i = 0; i < 5; i++)
        #pragma unroll
        for (int e = 0; e < 4; e++) acc[i][e] = (floatx4){0.f, 0.f, 0.f, 0.f};
    const bf16_t* Wb = Wbase0 + lane * 8;
    const bf16_t* Hb = Hsrc + lane * 8;
    #pragma unroll 2
    for (int ks = 0; ks < KSN; ks++) {
        bf16x8 hb0 = *(const bf16x8*)(Hb + ks * 512);
        bf16x8 hb1 = *(const bf16x8*)(Hb + ks * 512 + SE);
        bf16x8 hb2 = *(const bf16x8*)(Hb + ks * 512 + 2 * SE);
        bf16x8 hb3 = *(const bf16x8*)(Hb + ks * 512 + 3 * SE);
        #pragma unroll
        for (int i = 0; i < 5; i++) {
            bf16x8 wf = *(const bf16x8*)(Wb + i * (KSN * 512) + ks * 512);
            acc[i][0] = mfma16(wf, hb0, acc[i][0]);
            acc[i][1] = mfma16(wf, hb1, acc[i][1]);
            acc[i][2] = mfma16(wf, hb2, acc[i][2]);
            acc[i][3] = mfma16(wf, hb3, acc[i][3]);
        }
    }
}

// Epilogue: bias + relu + pack to bf16, write in B-frag order.
// C/D layout: n(edge)=lane&15, m(feat)=(lane>>4)*4+reg  (verified, absmax 0).
__device__ __forceinline__ void epi5(
    bf16_t* __restrict__ Hf, const float* __restrict__ bias,
    int w, int q, int l16, const floatx4 (&acc)[5][4]) {
    #pragma unroll
    for (int i = 0; i < 5; i++) {
        int n0 = (5 * w + i) * 16 + 4 * q;
        floatx4 bv = (n0 < HIDDEN) ? *(const floatx4*)&bias[n0]
                                   : (floatx4){0.f, 0.f, 0.f, 0.f};
        int ks = n0 >> 5, lp = l16 + 16 * ((n0 >> 3) & 3), j0 = n0 & 7;
        #pragma unroll
        for (int e = 0; e < 4; e++) {
            bf16x4 pk;
            #pragma unroll
            for (int r = 0; r < 4; r++)
                pk[r] = (bf16_t)fmaxf(acc[i][e][r] + bv[r], 0.f);
            *(bf16x4*)&Hf[((e * KS_H + ks) * 64 + lp) * 8 + j0] = pk;
        }
    }
}

// ---------------- fused edge MLP + KL ------------------------------------------
// OPERAND SWAP: D = mfma(A=W_frag, B=H_frag) -> D rows = features, cols = edges.
// H lives in LDS in exact B-fragment order Hf[e][ks][lane][8] -> every read is a
// wave-contiguous 1KB ds_read_b128, every epilogue write is one ds_write_b64.
// 4 waves x 256 threads; GEMM1/2: 20 jobs/wave exact; GEMM3: 13 jobs/wave exact
// (3 full nt x 4et + single-et job on tile 12, et = w).
__global__ __launch_bounds__(256, 3) void mlp_kernel(
    const float* __restrict__ x, const int* __restrict__ ei,
    const bf16_t* __restrict__ W1P, const bf16_t* __restrict__ W2P,
    const bf16_t* __restrict__ W3P,
    const float* __restrict__ b1, const float* __restrict__ b2,
    const float* __restrict__ b3, float* __restrict__ out) {
    __shared__ __align__(16) bf16_t A1f[4 * 64 * 8];          // 4 KB, frag order
    __shared__ __align__(16) bf16_t Hf[4 * KS_H * 64 * 8];    // 40 KB, frag order
    __shared__ float red[4];

    const int tid  = threadIdx.x;
    const int w    = tid >> 6, lane = tid & 63;
    const int q    = lane >> 4, l16 = lane & 15;
    const long e0 = (long)blockIdx.x * MT;

    // gather with embedded zero-padding (k>=12 rows zeroed by spare threads) —
    // all A1f writes are disjoint, single barrier after.
    if (tid < 2 * MT) {
        int m = tid >> 1, side = tid & 1;
        int node = ei[(long)side * N_EDGES + e0 + m];
        const float2* xr = (const float2*)(x + (long)node * D_FEAT);
        float2 v0 = xr[0], v1 = xr[1], v2 = xr[2];
        int et = m >> 4, ml = m & 15;
        bf16_t* Ab = &A1f[(et * 64 + ml) * 8];
        if (side == 0) {                       // k = 0..5 -> row ml, j 0..5
            bf16x4 lo = {(bf16_t)v0.x, (bf16_t)v0.y, (bf16_t)v1.x, (bf16_t)v1.y};
            *(bf16x4*)&Ab[0] = lo;
            bf16x2 mid = {(bf16_t)v2.x, (bf16_t)v2.y};
            *(bf16x2*)&Ab[4] = mid;
        } else {                               // k = 6,7 -> row ml; k = 8..11 -> row ml+16 (+zeros)
            bf16x2 hi2 = {(bf16_t)v0.x, (bf16_t)v0.y};
            *(bf16x2*)&Ab[6] = hi2;
            bf16x8 top = {(bf16_t)v1.x, (bf16_t)v1.y, (bf16_t)v2.x, (bf16_t)v2.y,
                          (bf16_t)0.f, (bf16_t)0.f, (bf16_t)0.f, (bf16_t)0.f};
            *(bf16x8*)&A1f[(et * 64 + ml + 16) * 8] = top;
        }
    } else {                                   // zero rows lane>=32 (k 16..31)
        int idx = tid - 128;                   // 0..127
        int et = idx >> 5, lr = 32 + (idx & 31);
        bf16x8 z = {};
        *(bf16x8*)&A1f[(et * 64 + lr) * 8] = z;
    }
    __syncthreads();

    floatx4 acc[5][4];

    // ---- GEMM1: h1 = relu(e @ W1 + b1), K=32 (one step) ----
    gemm5x4<1, 512>(W1P + (5 * w) * 512, A1f, lane, acc);
    epi5(Hf, b1, w, q, l16, acc);
    __syncthreads();

    // ---- GEMM2: h2 = relu(h1 @ W2 + b2), K=320 ----
    gemm5x4<KS_H, KS_H * 512>(W2P + (5 * w) * (KS_H * 512), Hf, lane, acc);
    __syncthreads();   // all Hf(h1) reads done before overwrite
    epi5(Hf, b2, w, q, l16, acc);
    __syncthreads();

    // ---- GEMM3: messages = h2 @ W3 + b3, KL in-register ----
    floatx4 a3[3][4], aq;
    #pragma unroll
    for (int t = 0; t < 3; t++)
        #pragma unroll
        for (int e = 0; e < 4; e++) a3[t][e] = (floatx4){0.f, 0.f, 0.f, 0.f};
    aq = (floatx4){0.f, 0.f, 0.f, 0.f};
    {
        const bf16_t* W3b = W3P + (3 * w) * (KS_H * 512) + lane * 8;
        const bf16_t* Wqb = W3P + 12 * (KS_H * 512) + lane * 8;
        const bf16_t* Hb  = Hf + lane * 8;
        const bf16_t* Hq  = Hf + w * (KS_H * 512) + lane * 8;   // et = w fragment
        #pragma unroll 2
        for (int ks = 0; ks < KS_H; ks++) {
            bf16x8 hb0 = *(const bf16x8*)(Hb + ks * 512);
            bf16x8 hb1 = *(const bf16x8*)(Hb + ks * 512 + KS_H * 512);
            bf16x8 hb2 = *(const bf16x8*)(Hb + ks * 512 + 2 * KS_H * 512);
            bf16x8 hb3 = *(const bf16x8*)(Hb + ks * 512 + 3 * KS_H * 512);
            #pragma unroll
            for (int t = 0; t < 3; t++) {
                bf16x8 wf = *(const bf16x8*)(W3b + t * (KS_H * 512) + ks * 512);
                a3[t][0] = mfma16(wf, hb0, a3[t][0]);
                a3[t][1] = mfma16(wf, hb1, a3[t][1]);
                a3[t][2] = mfma16(wf, hb2, a3[t][2]);
                a3[t][3] = mfma16(wf, hb3, a3[t][3]);
            }
            bf16x8 wq = *(const bf16x8*)(Wqb + ks * 512);
            bf16x8 hq = *(const bf16x8*)(Hq + ks * 512);
            aq = mfma16(wq, hq, aq);
        }
    }
    float s = 0.f;
    #pragma unroll
    for (int t = 0; t < 3; t++) {
        int n0 = (3 * w + t) * 16 + 4 * q;            // 0..188, always valid
        floatx4 bv = *(const floatx4*)&b3[n0];
        bool is_mu = (n0 < MSG);                      // 4-runs never straddle 100
        #pragma unroll
        for (int e = 0; e < 4; e++)
            #pragma unroll
            for (int r = 0; r < 4; r++) {
                float v = a3[t][e][r] + bv[r];
                if (is_mu) s += 0.5f * v * v;
                else       s += 0.5f * (__expf(v) - v - 1.f);
            }
    }
    {
        int n0q = 192 + 4 * q;                        // tile 12, logvar only
        if (n0q < OUTC) {
            floatx4 bq = *(const floatx4*)&b3[n0q];
            #pragma unroll
            for (int r = 0; r < 4; r++) {
                float v = aq[r] + bq[r];
                s += 0.5f * (__expf(v) - v - 1.f);
            }
        }
    }
    #pragma unroll
    for (int off = 32; off; off >>= 1) s += __shfl_down(s, off);
    if (lane == 0) red[w] = s;
    __syncthreads();
    if (tid == 0)
        atomicAdd(out, (red[0] + red[1] + red[2] + red[3]) * (1.0f / N_EDGES));
}

extern "C" void kernel_launch(void* const* d_in, const int* in_sizes, int n_in,
                              void* d_out, int out_size, void* d_ws, size_t ws_size,
                              hipStream_t stream) {
    const float* x      = (const float*)d_in[0];
    const int*   ei     = (const int*)d_in[1];
    const float* y      = (const float*)d_in[2];
    const float* target = (const float*)d_in[3];
    const float* W1     = (const float*)d_in[4];
    const float* b1     = (const float*)d_in[5];
    const float* W2     = (const float*)d_in[6];
    const float* b2     = (const float*)d_in[7];
    const float* W3     = (const float*)d_in[8];
    const float* b3     = (const float*)d_in[9];
    float* out = (float*)d_out;

    bf16_t* W1P = (bf16_t*)d_ws;
    bf16_t* W2P = W1P + NT_H * 512;
    bf16_t* W3P = W2P + NT_H * KS_H * 512;

    hipMemsetAsync(d_out, 0, sizeof(float), stream);
    prep_kernel<<<PREP_BLOCKS + LOSS_BLOCKS, 256, 0, stream>>>(
        W1, W2, W3, W1P, W2P, W3P, y, target, out);
    mlp_kernel<<<N_EDGES / MT, 256, 0, stream>>>(x, ei, W1P, W2P, W3P, b1, b2, b3, out);
}

// Round 3
// 402.262 us; speedup vs baseline: 1.1389x; 1.0218x over previous
//
#include <hip/hip_runtime.h>

#define N_NODES 100000
#define N_EDGES 1000000
#define D_FEAT  6
#define HIDDEN  300
#define HID_P   320          // padded hidden (multiple of 32)
#define MSG     100
#define OUTC    200          // 2*MSG
#define OUTC_P  208
#define MT      64           // edges per block
#define NT_H    (HID_P/16)   // 20 feature tiles for hidden layers
#define NT_M    13           // 13 feature tiles for messages (tile 12 partial)
#define KS_H    (HID_P/32)   // 10 k-steps of 32

typedef __bf16 bf16_t;
typedef __bf16 bf16x8 __attribute__((ext_vector_type(8)));
typedef __bf16 bf16x4 __attribute__((ext_vector_type(4)));
typedef __bf16 bf16x2 __attribute__((ext_vector_type(2)));
typedef float  floatx4 __attribute__((ext_vector_type(4)));

// ---------------- prep (weight pack) + base MAE loss, merged --------------------
// B-frag order pack (doubles as A-frag order under operand swap — same index map):
// chunk of 512 el = one (ft,ks) fragment: el = ((ft*KS+ks)*64+lane)*8+j,
// element = W[k][n], n = ft*16+(lane&15), k = ks*32+(lane>>4)*8+j, zero-padded.
#define PREP_BLOCKS 700
#define LOSS_BLOCKS 200
__global__ void prep_kernel(const float* __restrict__ W1, const float* __restrict__ W2,
                            const float* __restrict__ W3, bf16_t* __restrict__ W1P,
                            bf16_t* __restrict__ W2P, bf16_t* __restrict__ W3P,
                            const float* __restrict__ y, const float* __restrict__ t,
                            float* __restrict__ out) {
    if (blockIdx.x >= PREP_BLOCKS) {
        float s = 0.f;
        for (int i = (blockIdx.x - PREP_BLOCKS) * blockDim.x + threadIdx.x;
             i < N_NODES * 2; i += LOSS_BLOCKS * blockDim.x)
            s += fabsf(y[i] - t[i]);
        #pragma unroll
        for (int off = 32; off; off >>= 1) s += __shfl_down(s, off);
        __shared__ float red[4];
        if ((threadIdx.x & 63) == 0) red[threadIdx.x >> 6] = s;
        __syncthreads();
        if (threadIdx.x == 0)
            atomicAdd(out, (red[0] + red[1] + red[2] + red[3]) * (1.0f / N_NODES));
        return;
    }
    const int n1 = NT_H * 512;
    const int n2 = NT_H * KS_H * 512;
    const int n3 = NT_M * KS_H * 512;
    const int total = n1 + n2 + n3;
    for (int id = blockIdx.x * blockDim.x + threadIdx.x; id < total;
         id += PREP_BLOCKS * blockDim.x) {
        if (id < n1) {
            int nt = id >> 9, rem = id & 511, lane = rem >> 3, j = rem & 7;
            int n = nt * 16 + (lane & 15), k = (lane >> 4) * 8 + j;
            float v = (n < HIDDEN && k < 2 * D_FEAT) ? W1[k * HIDDEN + n] : 0.f;
            W1P[id] = (bf16_t)v;
        } else if (id < n1 + n2) {
            int r = id - n1;
            int chunk = r >> 9, rem = r & 511, lane = rem >> 3, j = rem & 7;
            int ks = chunk % KS_H, nt = chunk / KS_H;
            int n = nt * 16 + (lane & 15), k = ks * 32 + (lane >> 4) * 8 + j;
            float v = (n < HIDDEN && k < HIDDEN) ? W2[k * HIDDEN + n] : 0.f;
            W2P[r] = (bf16_t)v;
        } else {
            int r = id - n1 - n2;
            int chunk = r >> 9, rem = r & 511, lane = rem >> 3, j = rem & 7;
            int ks = chunk % KS_H, nt = chunk / KS_H;
            int n = nt * 16 + (lane & 15), k = ks * 32 + (lane >> 4) * 8 + j;
            float v = (n < OUTC && k < HIDDEN) ? W3[k * OUTC + n] : 0.f;
            W3P[r] = (bf16_t)v;
        }
    }
}

static __device__ __forceinline__ floatx4 mfma16(bf16x8 a, bf16x8 b, floatx4 c) {
    return __builtin_amdgcn_mfma_f32_16x16x32_bf16(a, b, c, 0, 0, 0);
}

// GEMM phase, 4-wave decomposition: wave w owns nts {5w..5w+4} x all 4 edge
// tiles = 20 jobs/wave, exactly balanced. BIAS RIDES IN C: acc[i][e] is
// initialized with the bias fragment for nt i (same for all e; C/D row = feat),
// so no epilogue/KL bias adds are needed. D = A*B + C is f32-exact equivalent.
template<int KSN, int SE>
__device__ __forceinline__ void gemm5x4(
    const bf16_t* __restrict__ Wbase0,     // W pack + (5w)*KSN*512
    const bf16_t* __restrict__ Hsrc, int lane,
    const floatx4 (&binit)[5], floatx4 (&acc)[5][4]) {
    #pragma unroll
    for (int i = 0; i < 5; i++)
        #pragma unroll
        for (int e = 0; e < 4; e++) acc[i][e] = binit[i];
    const bf16_t* Wb = Wbase0 + lane * 8;
    const bf16_t* Hb = Hsrc + lane * 8;
    #pragma unroll 2
    for (int ks = 0; ks < KSN; ks++) {
        bf16x8 hb0 = *(const bf16x8*)(Hb + ks * 512);
        bf16x8 hb1 = *(const bf16x8*)(Hb + ks * 512 + SE);
        bf16x8 hb2 = *(const bf16x8*)(Hb + ks * 512 + 2 * SE);
        bf16x8 hb3 = *(const bf16x8*)(Hb + ks * 512 + 3 * SE);
        #pragma unroll
        for (int i = 0; i < 5; i++) {
            bf16x8 wf = *(const bf16x8*)(Wb + i * (KSN * 512) + ks * 512);
            acc[i][0] = mfma16(wf, hb0, acc[i][0]);
            acc[i][1] = mfma16(wf, hb1, acc[i][1]);
            acc[i][2] = mfma16(wf, hb2, acc[i][2]);
            acc[i][3] = mfma16(wf, hb3, acc[i][3]);
        }
    }
}

// Epilogue: relu + pack to bf16 (bias already accumulated in C), B-frag order.
// C/D layout: n(edge)=lane&15, m(feat)=(lane>>4)*4+reg  (verified, absmax 0).
__device__ __forceinline__ void epi5(
    bf16_t* __restrict__ Hf, int w, int q, int l16, const floatx4 (&acc)[5][4]) {
    #pragma unroll
    for (int i = 0; i < 5; i++) {
        int n0 = (5 * w + i) * 16 + 4 * q;
        int ks = n0 >> 5, lp = l16 + 16 * ((n0 >> 3) & 3), j0 = n0 & 7;
        #pragma unroll
        for (int e = 0; e < 4; e++) {
            bf16x4 pk;
            #pragma unroll
            for (int r = 0; r < 4; r++)
                pk[r] = (bf16_t)fmaxf(acc[i][e][r], 0.f);
            *(bf16x4*)&Hf[((e * KS_H + ks) * 64 + lp) * 8 + j0] = pk;
        }
    }
}

// ---------------- fused edge MLP + KL ------------------------------------------
// OPERAND SWAP: D = mfma(A=W_frag, B=H_frag) -> D rows = features, cols = edges.
// H lives in LDS in exact B-fragment order Hf[e][ks][lane][8] -> every read is a
// wave-contiguous 1KB ds_read_b128, every epilogue write is one ds_write_b64.
// 4 waves x 256 threads; GEMM1/2: 20 jobs/wave exact; GEMM3: 13 jobs/wave exact
// (3 full nt x 4et + single-et job on tile 12, et = w).
__global__ __launch_bounds__(256, 3) void mlp_kernel(
    const float* __restrict__ x, const int* __restrict__ ei,
    const bf16_t* __restrict__ W1P, const bf16_t* __restrict__ W2P,
    const bf16_t* __restrict__ W3P,
    const float* __restrict__ b1, const float* __restrict__ b2,
    const float* __restrict__ b3, float* __restrict__ out) {
    __shared__ __align__(16) bf16_t A1f[4 * 64 * 8];          // 4 KB, frag order
    __shared__ __align__(16) bf16_t Hf[4 * KS_H * 64 * 8];    // 40 KB, frag order
    __shared__ float red[4];

    const int tid  = threadIdx.x;
    const int w    = tid >> 6, lane = tid & 63;
    const int q    = lane >> 4, l16 = lane & 15;
    const long e0 = (long)blockIdx.x * MT;

    // ---- preload W1 fragments + bias C-init vectors (independent of gather;
    // issued before the barrier so L2 latency hides under the gather) ----
    bf16x8 wf1[5];
    floatx4 bv1[5], bv2[5];
    #pragma unroll
    for (int i = 0; i < 5; i++) {
        wf1[i] = *(const bf16x8*)&W1P[((5 * w + i) * 64 + lane) * 8];
        int n0 = (5 * w + i) * 16 + 4 * q;
        bv1[i] = (n0 < HIDDEN) ? *(const floatx4*)&b1[n0] : (floatx4){0.f, 0.f, 0.f, 0.f};
        bv2[i] = (n0 < HIDDEN) ? *(const floatx4*)&b2[n0] : (floatx4){0.f, 0.f, 0.f, 0.f};
    }

    // gather with embedded zero-padding (k>=12 rows zeroed by spare threads) —
    // all A1f writes are disjoint, single barrier after.
    if (tid < 2 * MT) {
        int m = tid >> 1, side = tid & 1;
        int node = ei[(long)side * N_EDGES + e0 + m];
        const float2* xr = (const float2*)(x + (long)node * D_FEAT);
        float2 v0 = xr[0], v1 = xr[1], v2 = xr[2];
        int et = m >> 4, ml = m & 15;
        bf16_t* Ab = &A1f[(et * 64 + ml) * 8];
        if (side == 0) {                       // k = 0..5 -> row ml, j 0..5
            bf16x4 lo = {(bf16_t)v0.x, (bf16_t)v0.y, (bf16_t)v1.x, (bf16_t)v1.y};
            *(bf16x4*)&Ab[0] = lo;
            bf16x2 mid = {(bf16_t)v2.x, (bf16_t)v2.y};
            *(bf16x2*)&Ab[4] = mid;
        } else {                               // k = 6,7 -> row ml; k = 8..11 -> row ml+16 (+zeros)
            bf16x2 hi2 = {(bf16_t)v0.x, (bf16_t)v0.y};
            *(bf16x2*)&Ab[6] = hi2;
            bf16x8 top = {(bf16_t)v1.x, (bf16_t)v1.y, (bf16_t)v2.x, (bf16_t)v2.y,
                          (bf16_t)0.f, (bf16_t)0.f, (bf16_t)0.f, (bf16_t)0.f};
            *(bf16x8*)&A1f[(et * 64 + ml + 16) * 8] = top;
        }
    } else {                                   // zero rows lane>=32 (k 16..31)
        int idx = tid - 128;                   // 0..127
        int et = idx >> 5, lr = 32 + (idx & 31);
        bf16x8 z = {};
        *(bf16x8*)&A1f[(et * 64 + lr) * 8] = z;
    }
    __syncthreads();

    floatx4 acc[5][4];

    // ---- GEMM1: h1 = relu(e @ W1 + b1), K=32 (one step), W1 preloaded ----
    {
        bf16x8 hb0 = *(const bf16x8*)&A1f[lane * 8];
        bf16x8 hb1 = *(const bf16x8*)&A1f[(64 + lane) * 8];
        bf16x8 hb2 = *(const bf16x8*)&A1f[(128 + lane) * 8];
        bf16x8 hb3 = *(const bf16x8*)&A1f[(192 + lane) * 8];
        #pragma unroll
        for (int i = 0; i < 5; i++) {
            acc[i][0] = mfma16(wf1[i], hb0, bv1[i]);
            acc[i][1] = mfma16(wf1[i], hb1, bv1[i]);
            acc[i][2] = mfma16(wf1[i], hb2, bv1[i]);
            acc[i][3] = mfma16(wf1[i], hb3, bv1[i]);
        }
    }
    epi5(Hf, w, q, l16, acc);
    __syncthreads();

    // ---- GEMM2: h2 = relu(h1 @ W2 + b2), K=320, bias in C ----
    gemm5x4<KS_H, KS_H * 512>(W2P + (5 * w) * (KS_H * 512), Hf, lane, bv2, acc);
    __syncthreads();   // all Hf(h1) reads done before overwrite
    epi5(Hf, w, q, l16, acc);
    __syncthreads();

    // ---- GEMM3: messages = h2 @ W3 + b3 (bias in C), KL in-register ----
    floatx4 a3[3][4], aq;
    const int n0q = 192 + 4 * q;                  // tile 12, logvar only
    {
        #pragma unroll
        for (int t = 0; t < 3; t++) {
            int n0 = (3 * w + t) * 16 + 4 * q;    // 0..191, always valid
            floatx4 bv = *(const floatx4*)&b3[n0];
            #pragma unroll
            for (int e = 0; e < 4; e++) a3[t][e] = bv;
        }
        aq = (n0q < OUTC) ? *(const floatx4*)&b3[n0q] : (floatx4){0.f, 0.f, 0.f, 0.f};
    }
    {
        const bf16_t* W3b = W3P + (3 * w) * (KS_H * 512) + lane * 8;
        const bf16_t* Wqb = W3P + 12 * (KS_H * 512) + lane * 8;
        const bf16_t* Hb  = Hf + lane * 8;
        const bf16_t* Hq  = Hf + w * (KS_H * 512) + lane * 8;   // et = w fragment
        #pragma unroll 2
        for (int ks = 0; ks < KS_H; ks++) {
            bf16x8 hb0 = *(const bf16x8*)(Hb + ks * 512);
            bf16x8 hb1 = *(const bf16x8*)(Hb + ks * 512 + KS_H * 512);
            bf16x8 hb2 = *(const bf16x8*)(Hb + ks * 512 + 2 * KS_H * 512);
            bf16x8 hb3 = *(const bf16x8*)(Hb + ks * 512 + 3 * KS_H * 512);
            #pragma unroll
            for (int t = 0; t < 3; t++) {
                bf16x8 wf = *(const bf16x8*)(W3b + t * (KS_H * 512) + ks * 512);
                a3[t][0] = mfma16(wf, hb0, a3[t][0]);
                a3[t][1] = mfma16(wf, hb1, a3[t][1]);
                a3[t][2] = mfma16(wf, hb2, a3[t][2]);
                a3[t][3] = mfma16(wf, hb3, a3[t][3]);
            }
            bf16x8 wq = *(const bf16x8*)(Wqb + ks * 512);
            bf16x8 hq = *(const bf16x8*)(Hq + ks * 512);
            aq = mfma16(wq, hq, aq);
        }
    }
    // KL: mu -> sm += v*v (1 fmac); logvar -> se += exp(v), sv += v, cnt += 16
    // per group. total = 0.5*(sm + se - sv - cnt).
    float sm = 0.f, se = 0.f, sv = 0.f, cnt = 0.f;
    #pragma unroll
    for (int t = 0; t < 3; t++) {
        int n0 = (3 * w + t) * 16 + 4 * q;
        if (n0 < MSG) {                           // 4-runs never straddle 100
            #pragma unroll
            for (int e = 0; e < 4; e++)
                #pragma unroll
                for (int r = 0; r < 4; r++) {
                    float v = a3[t][e][r];
                    sm += v * v;
                }
        } else {
            #pragma unroll
            for (int e = 0; e < 4; e++)
                #pragma unroll
                for (int r = 0; r < 4; r++) {
                    float v = a3[t][e][r];
                    se += __expf(v);
                    sv += v;
                }
            cnt += 16.f;
        }
    }
    if (n0q < OUTC) {
        #pragma unroll
        for (int r = 0; r < 4; r++) {
            float v = aq[r];
            se += __expf(v);
            sv += v;
        }
        cnt += 4.f;
    }
    float s = sm + se - sv - cnt;
    #pragma unroll
    for (int off = 32; off; off >>= 1) s += __shfl_down(s, off);
    if (lane == 0) red[w] = s;
    __syncthreads();
    if (tid == 0)
        atomicAdd(out, (red[0] + red[1] + red[2] + red[3]) * (0.5f / N_EDGES));
}

extern "C" void kernel_launch(void* const* d_in, const int* in_sizes, int n_in,
                              void* d_out, int out_size, void* d_ws, size_t ws_size,
                              hipStream_t stream) {
    const float* x      = (const float*)d_in[0];
    const int*   ei     = (const int*)d_in[1];
    const float* y      = (const float*)d_in[2];
    const float* target = (const float*)d_in[3];
    const float* W1     = (const float*)d_in[4];
    const float* b1     = (const float*)d_in[5];
    const float* W2     = (const float*)d_in[6];
    const float* b2     = (const float*)d_in[7];
    const float* W3     = (const float*)d_in[8];
    const float* b3     = (const float*)d_in[9];
    float* out = (float*)d_out;

    bf16_t* W1P = (bf16_t*)d_ws;
    bf16_t* W2P = W1P + NT_H * 512;
    bf16_t* W3P = W2P + NT_H * KS_H * 512;

    hipMemsetAsync(d_out, 0, sizeof(float), stream);
    prep_kernel<<<PREP_BLOCKS + LOSS_BLOCKS, 256, 0, stream>>>(
        W1, W2, W3, W1P, W2P, W3P, y, target, out);
    mlp_kernel<<<N_EDGES / MT, 256, 0, stream>>>(x, ei, W1P, W2P, W3P, b1, b2, b3, out);
}